// Round 1
// baseline (200.500 us; speedup 1.0000x reference)
//
#include <hip/hip_runtime.h>

// Problem: BATCH=256, GRIDS=16384, TYPES=8
//   p = pred_hz[:, :, 0]                       (stride-8 float32 gather)
//   ll = sum(target ? log(p) : log1p(-p))
//   out = -ll / 256                            (single float32 scalar)
//
// Memory-bound: all 64B lines of the 128MiB pred array contain a needed
// element (stride 32B), so the HBM floor is ~128MiB + mask.

#define NLL_ELEMS (256 * 16384)        // 4,194,304 mask elements
#define NLL_PER_THREAD 8
#define NLL_BLOCK 256
#define NLL_GRID (NLL_ELEMS / NLL_PER_THREAD / NLL_BLOCK)  // 2048 blocks exactly

__global__ __launch_bounds__(NLL_BLOCK) void nll_partial_kernel(
    const float* __restrict__ pred,    // [ELEMS * 8] floats, we need index e*8
    const int*   __restrict__ mask,    // [ELEMS] int32 (bool promoted by harness)
    float*       __restrict__ partial) // [NLL_GRID]
{
    const int tid = blockIdx.x * NLL_BLOCK + threadIdx.x;
    const long long base = (long long)tid * NLL_PER_THREAD;

    // Vectorized mask load: 2 x int4 = 8 ints, fully coalesced.
    const int4* mask4 = (const int4*)mask;
    int4 m0 = mask4[tid * 2 + 0];
    int4 m1 = mask4[tid * 2 + 1];
    int ms[8] = {m0.x, m0.y, m0.z, m0.w, m1.x, m1.y, m1.z, m1.w};

    float s = 0.0f;
#pragma unroll
    for (int k = 0; k < NLL_PER_THREAD; ++k) {
        // pred element for mask index e is at e*8 (t=0 slot), stride 32B.
        float p = pred[(base + k) * 8];
        float v = ms[k] ? p : (1.0f - p);
        s += __logf(v);
    }

    // Wave(64) shuffle reduction.
#pragma unroll
    for (int off = 32; off > 0; off >>= 1)
        s += __shfl_down(s, off, 64);

    __shared__ float lds[NLL_BLOCK / 64];
    const int lane = threadIdx.x & 63;
    const int wv   = threadIdx.x >> 6;
    if (lane == 0) lds[wv] = s;
    __syncthreads();
    if (threadIdx.x == 0)
        partial[blockIdx.x] = lds[0] + lds[1] + lds[2] + lds[3];
}

__global__ __launch_bounds__(256) void nll_final_kernel(
    const float* __restrict__ partial,  // [NLL_GRID]
    float*       __restrict__ out)
{
    // NLL_GRID = 2048 partials, 256 threads x 8 each.
    float s = 0.0f;
    const float4* p4 = (const float4*)partial;
#pragma unroll
    for (int k = 0; k < 2; ++k) {
        float4 v = p4[threadIdx.x * 2 + k];
        s += v.x + v.y + v.z + v.w;
    }
#pragma unroll
    for (int off = 32; off > 0; off >>= 1)
        s += __shfl_down(s, off, 64);

    __shared__ float lds[4];
    const int lane = threadIdx.x & 63;
    const int wv   = threadIdx.x >> 6;
    if (lane == 0) lds[wv] = s;
    __syncthreads();
    if (threadIdx.x == 0) {
        float total = lds[0] + lds[1] + lds[2] + lds[3];
        out[0] = -total * (1.0f / 256.0f);   // -ll / batch
    }
}

extern "C" void kernel_launch(void* const* d_in, const int* in_sizes, int n_in,
                              void* d_out, int out_size, void* d_ws, size_t ws_size,
                              hipStream_t stream)
{
    const float* pred = (const float*)d_in[0];
    const int*   mask = (const int*)d_in[1];
    float* partial = (float*)d_ws;            // needs NLL_GRID*4 = 8 KiB scratch
    float* out = (float*)d_out;

    nll_partial_kernel<<<NLL_GRID, NLL_BLOCK, 0, stream>>>(pred, mask, partial);
    nll_final_kernel<<<1, 256, 0, stream>>>(partial, out);
}